// Round 3
// baseline (207.663 us; speedup 1.0000x reference)
//
#include <hip/hip_runtime.h>

// Problem constants
constexpr int cB = 64, cS = 512, cN = 512, cM = 128, cUNF = 6;
constexpr float cDELTA = 0.016666666666666666f;  // DT/UNFOLDS = 0.1/6

// Decomposition: 16 batch-groups (KB=4) x 16 j-tiles (JT=32) = 256 blocks.
// Block = 32 j-lanes x 32 i-chunks = 1024 threads (16 waves/CU).
constexpr int KB = 4;
constexpr int JT = 32;
constexpr int NJT = cN / JT;          // 16
constexpr int IC = 32;
constexpr int ILEN = cN / IC;         // 16
constexpr int NT = JT * IC;           // 1024
constexpr int NB = (cB / KB) * NJT;   // 256

// ws layout (float offsets)
constexpr size_t OFF_P4  = 0;                            // float4[N*N] {a,c,e,w}
constexpr size_t OFF_EW  = (size_t)cN * cN * 4;          // float2[N*N] {e,w}
constexpr size_t OFF_SRB = OFF_EW + (size_t)cN * cN * 2; // [B*N] s_rev + bias
constexpr size_t OFF_SW  = OFF_SRB + (size_t)cB * cN;    // [B*N] s_w
constexpr size_t OFF_VA  = OFF_SW  + (size_t)cB * cN;    // [B*N] v ping
constexpr size_t OFF_VB  = OFF_VA  + (size_t)cB * cN;    // [B*N] v pong
constexpr size_t OFF_CTR = OFF_VB  + (size_t)cB * cN;    // int[16]: [0..5]=barriers, [8]=nonuniform

__device__ __forceinline__ float clamp01(float x) {
    return __builtin_amdgcn_fmed3f(x, 0.0f, 1.0f);
}

// ---- k_init: pack P4/EW, probe gate uniformity, sensory reduction ----
__global__ __launch_bounds__(NT)
void k_init(const float* __restrict__ inputs, const float* __restrict__ bias,
            const float* __restrict__ erev,  const float* __restrict__ wgt,
            const float* __restrict__ sigma, const float* __restrict__ mu,
            const float* __restrict__ serev, const float* __restrict__ swgt,
            const float* __restrict__ ssigma,const float* __restrict__ smu,
            const float* __restrict__ mask,  const float* __restrict__ smask,
            const float* __restrict__ inw,   const float* __restrict__ inb,
            float* __restrict__ ws)
{
    float4* P4 = (float4*)(ws + OFF_P4);
    float2* EW = (float2*)(ws + OFF_EW);
    float* srb = ws + OFF_SRB;
    float* swS = ws + OFF_SW;
    int*   ctr = (int*)(ws + OFF_CTR);

    const int tid = threadIdx.x, bid = blockIdx.x;
    const int bg = bid >> 4, jt = bid & (NJT - 1);
    const int b0 = bg * KB, j0 = jt * JT;
    const int jl = tid & (JT - 1), ic = tid >> 5;
    const int j = j0 + jl;

    __shared__ float xsh[cS * KB];        // 8 KB, xsh[s*4+b]
    __shared__ float redR[KB * IC * JT];  // 16 KB
    __shared__ float redW[KB * IC * JT];  // 16 KB

    // P fill: exactly one element per thread (256*1024 == 512*512)
    {
        int idx  = bid * NT + tid;
        float sg = sigma[idx];
        float a  = 0.5f / sg;                 // 1/(2*sigma)
        float c  = fmaf(-mu[idx], a, 0.5f);   // 0.5 - mu/(2*sigma)
        float mk = mask[idx];
        float e  = erev[idx] * mk;
        float w  = wgt[idx]  * mk;
        P4[idx] = make_float4(a, c, e, w);
        EW[idx] = make_float2(e, w);
        int ok = (a == 1.0f) && (c == 0.0f);  // gate == clamp01(v), j-independent
        if (!__syncthreads_and(ok)) {
            if (tid == 0) atomicAdd(&ctr[8], 1);
        }
    }

    // stage x[b][s] = inputs*in_w + in_b as xsh[s*4+b]
#pragma unroll
    for (int r = 0; r < (cS * KB) / NT; ++r) {
        int t = tid + r * NT;
        int bb = t & 3, s = t >> 2;
        xsh[t] = fmaf(inputs[(b0 + bb) * cS + s], inw[s], inb[s]);
    }
    __syncthreads();

    float aR[KB] = {0.f, 0.f, 0.f, 0.f}, aW[KB] = {0.f, 0.f, 0.f, 0.f};
    int idx = (ic * ILEN) * cN + j;
    int xo  = (ic * ILEN) * KB;
#pragma unroll 4
    for (int ii = 0; ii < ILEN; ++ii, idx += cN, xo += KB) {
        float sg = ssigma[idx];
        float a  = 0.5f / sg;
        float c  = fmaf(-smu[idx], a, 0.5f);
        float mk = smask[idx];
        float e  = serev[idx] * mk;
        float wv = swgt[idx] * mk;
        const float4 xv = *(const float4*)&xsh[xo];
        float g;
        g = clamp01(fmaf(xv.x, a, c)); aR[0] = fmaf(g, e, aR[0]); aW[0] = fmaf(g, wv, aW[0]);
        g = clamp01(fmaf(xv.y, a, c)); aR[1] = fmaf(g, e, aR[1]); aW[1] = fmaf(g, wv, aW[1]);
        g = clamp01(fmaf(xv.z, a, c)); aR[2] = fmaf(g, e, aR[2]); aW[2] = fmaf(g, wv, aW[2]);
        g = clamp01(fmaf(xv.w, a, c)); aR[3] = fmaf(g, e, aR[3]); aW[3] = fmaf(g, wv, aW[3]);
    }
#pragma unroll
    for (int b = 0; b < KB; ++b) {
        redR[(b * IC + ic) * JT + jl] = aR[b];
        redW[(b * IC + ic) * JT + jl] = aW[b];
    }
    __syncthreads();

    if (tid < JT * KB) {
        int jj = tid & (JT - 1), bb = tid >> 5;
        float r = 0.f, wv = 0.f;
#pragma unroll
        for (int c2 = 0; c2 < IC; ++c2) {
            r  += redR[(bb * IC + c2) * JT + jj];
            wv += redW[(bb * IC + c2) * JT + jj];
        }
        int jg = j0 + jj;
        int gidx = (b0 + bb) * cN + jg;
        srb[gidx] = r + bias[jg];   // s_rev + b folded
        swS[gidx] = wv;
    }
}

// ---- k_unfolds: all 6 unfolds in one persistent kernel.
//      v exchanged via agent-scope (sc1) atomics that bypass the per-XCD L2s,
//      so barriers need NO acquire-invalidate -> P/EW stay hot in L2. ----
__global__ __launch_bounds__(NT)
void k_unfolds(const float* __restrict__ states, const float* __restrict__ tau,
               const float* __restrict__ outw,   const float* __restrict__ outb,
               float* __restrict__ out, float* __restrict__ ws)
{
    const float4* P4 = (const float4*)(ws + OFF_P4);
    const float2* EW = (const float2*)(ws + OFF_EW);
    const float* srb = ws + OFF_SRB;
    const float* swS = ws + OFF_SW;
    float* vA = ws + OFF_VA;
    float* vB = ws + OFF_VB;
    int*   ctr = (int*)(ws + OFF_CTR);

    const int tid = threadIdx.x, bid = blockIdx.x;
    const int bg = bid >> 4, jt = bid & (NJT - 1);
    const int b0 = bg * KB, j0 = jt * JT;
    const int jl = tid & (JT - 1), ic = tid >> 5;
    const int j = j0 + jl;

    __shared__ float vsh[cN * KB];        // 8 KB, vsh[i*4+b] (clamped in fast path)
    __shared__ float redR[KB * IC * JT];  // 16 KB
    __shared__ float redW[KB * IC * JT];  // 16 KB

    // epilogue scalars (owner threads: tid < 128 own (bb, jj))
    float my_srb = 0.f, my_sw = 0.f, my_tau = 0.f, my_ow = 0.f, my_ob = 0.f;
    int my_gidx = 0, my_mi = -1;
    if (tid < JT * KB) {
        int jj = tid & (JT - 1), bb = tid >> 5;
        int jg = j0 + jj;
        my_gidx = (b0 + bb) * cN + jg;
        my_srb  = srb[my_gidx];
        my_sw   = swS[my_gidx];
        my_tau  = tau[jg];
        if (jg >= cN - cM) {
            int m = jg - (cN - cM);
            my_ow = outw[m]; my_ob = outb[m];
            my_mi = (b0 + bb) * cM + m;
        }
    }
    const int fast = (ctr[8] == 0);   // written by k_init (previous dispatch)

    const float* vin = states;
    for (int u = 0; u < cUNF; ++u) {
        float* vout = (u == cUNF - 1) ? (out + cB * cM) : ((u & 1) ? vA : vB);

        // stage v (agent-scope atomic loads: always-fresh, bypass stale L2)
#pragma unroll
        for (int r = 0; r < (cN * KB) / NT; ++r) {   // 2 per thread
            int t = tid + r * NT;
            int bb = t & 3, ii = t >> 2;
            float vv = __hip_atomic_load(&vin[(b0 + bb) * cN + ii],
                                         __ATOMIC_RELAXED, __HIP_MEMORY_SCOPE_AGENT);
            vsh[t] = fast ? clamp01(vv) : vv;
        }
        __syncthreads();

        float aR[KB] = {0.f, 0.f, 0.f, 0.f}, aW[KB] = {0.f, 0.f, 0.f, 0.f};
        int idx = (ic * ILEN) * cN + j;
        int vo  = (ic * ILEN) * KB;
        if (fast) {
            // gate already applied at staging: pure dual-accumulate, 8 B/elem
#pragma unroll 8
            for (int ii = 0; ii < ILEN; ++ii, idx += cN, vo += KB) {
                const float2 ew = EW[idx];
                const float4 g4 = *(const float4*)&vsh[vo];
                aR[0] = fmaf(g4.x, ew.x, aR[0]); aW[0] = fmaf(g4.x, ew.y, aW[0]);
                aR[1] = fmaf(g4.y, ew.x, aR[1]); aW[1] = fmaf(g4.y, ew.y, aW[1]);
                aR[2] = fmaf(g4.z, ew.x, aR[2]); aW[2] = fmaf(g4.z, ew.y, aW[2]);
                aR[3] = fmaf(g4.w, ew.x, aR[3]); aW[3] = fmaf(g4.w, ew.y, aW[3]);
            }
        } else {
#pragma unroll 4
            for (int ii = 0; ii < ILEN; ++ii, idx += cN, vo += KB) {
                const float4 p  = P4[idx];
                const float4 vv = *(const float4*)&vsh[vo];
                float g;
                g = clamp01(fmaf(vv.x, p.x, p.y)); aR[0] = fmaf(g, p.z, aR[0]); aW[0] = fmaf(g, p.w, aW[0]);
                g = clamp01(fmaf(vv.y, p.x, p.y)); aR[1] = fmaf(g, p.z, aR[1]); aW[1] = fmaf(g, p.w, aW[1]);
                g = clamp01(fmaf(vv.z, p.x, p.y)); aR[2] = fmaf(g, p.z, aR[2]); aW[2] = fmaf(g, p.w, aW[2]);
                g = clamp01(fmaf(vv.w, p.x, p.y)); aR[3] = fmaf(g, p.z, aR[3]); aW[3] = fmaf(g, p.w, aW[3]);
            }
        }
#pragma unroll
        for (int b = 0; b < KB; ++b) {
            redR[(b * IC + ic) * JT + jl] = aR[b];
            redW[(b * IC + ic) * JT + jl] = aW[b];
        }
        __syncthreads();

        if (tid < JT * KB) {
            int jj = tid & (JT - 1), bb = tid >> 5;
            float r = 0.f, wv = 0.f;
#pragma unroll
            for (int c2 = 0; c2 < IC; ++c2) {
                r  += redR[(bb * IC + c2) * JT + jj];
                wv += redW[(bb * IC + c2) * JT + jj];
            }
            r  += my_srb;
            wv += my_sw;
            float k    = 1.0f / (1.0f + wv);
            float taun = my_tau * k;
            float inv  = 1.0f / (taun + cDELTA);
            float vold = __hip_atomic_load(&vin[my_gidx],
                                           __ATOMIC_RELAXED, __HIP_MEMORY_SCOPE_AGENT);
            float vn = (taun * inv) * vold + (cDELTA * inv) * k * r;
            if (u == cUNF - 1) {
                vout[my_gidx] = vn;                       // plain: dispatch-end flush
                if (my_mi >= 0) out[my_mi] = fmaf(vn, my_ow, my_ob);
            } else {
                __hip_atomic_store(&vout[my_gidx], vn,
                                   __ATOMIC_RELAXED, __HIP_MEMORY_SCOPE_AGENT);
            }
        }

        if (u < cUNF - 1) {
            __syncthreads();   // drains vmcnt -> all block's v-stores at coherence point
            if (tid == 0) {
                __hip_atomic_fetch_add(&ctr[u], 1, __ATOMIC_RELEASE, __HIP_MEMORY_SCOPE_AGENT);
                while (__hip_atomic_load(&ctr[u], __ATOMIC_RELAXED, __HIP_MEMORY_SCOPE_AGENT) < NB)
                    __builtin_amdgcn_s_sleep(2);
            }
            __syncthreads();
            vin = (u & 1) ? vA : vB;   // the buffer just produced
        }
    }
}

extern "C" void kernel_launch(void* const* d_in, const int* in_sizes, int n_in,
                              void* d_out, int out_size, void* d_ws, size_t ws_size,
                              hipStream_t stream)
{
    const float* inputs = (const float*)d_in[0];
    const float* states = (const float*)d_in[1];
    const float* tau    = (const float*)d_in[2];
    const float* bias   = (const float*)d_in[3];
    const float* erev   = (const float*)d_in[4];
    const float* wgt    = (const float*)d_in[5];
    const float* sigma  = (const float*)d_in[6];
    const float* mu     = (const float*)d_in[7];
    const float* serev  = (const float*)d_in[8];
    const float* swgt   = (const float*)d_in[9];
    const float* ssigma = (const float*)d_in[10];
    const float* smu    = (const float*)d_in[11];
    const float* mask   = (const float*)d_in[12];
    const float* smask  = (const float*)d_in[13];
    const float* inw    = (const float*)d_in[14];
    const float* inb    = (const float*)d_in[15];
    const float* outw   = (const float*)d_in[16];
    const float* outb   = (const float*)d_in[17];
    float* out = (float*)d_out;
    float* ws  = (float*)d_ws;

    int* ctr = (int*)(ws + OFF_CTR);
    hipMemsetAsync(ctr, 0, 16 * sizeof(int), stream);   // barrier counters + flag

    k_init<<<NB, NT, 0, stream>>>(inputs, bias, erev, wgt, sigma, mu,
                                  serev, swgt, ssigma, smu, mask, smask,
                                  inw, inb, ws);

    void* args[] = {(void*)&states, (void*)&tau, (void*)&outw, (void*)&outb,
                    (void*)&out, (void*)&ws};
    // cooperative launch solely for the co-residency guarantee; cg::sync never used
    hipLaunchCooperativeKernel((const void*)k_unfolds, dim3(NB), dim3(NT),
                               args, 0, stream);
}